// Round 1
// baseline (440.849 us; speedup 1.0000x reference)
//
#include <hip/hip_runtime.h>
#include <cstdint>

typedef __bf16 bf16x8 __attribute__((ext_vector_type(8)));
typedef float  f32x4  __attribute__((ext_vector_type(4)));

#define MFMA16(a, b, c) __builtin_amdgcn_mfma_f32_16x16x32_bf16((a), (b), (c), 0, 0, 0)

__device__ __forceinline__ float fsig(float x) {
    // 1/(1+exp(-x)) via exp2/rcp (v_exp_f32 + v_rcp_f32)
    float e = __builtin_amdgcn_exp2f(-1.4426950408889634f * x);
    return __builtin_amdgcn_rcpf(1.0f + e);
}
__device__ __forceinline__ float ftanh(float x) {
    // tanh(x) = 2/(1+exp(-2x)) - 1
    float e = __builtin_amdgcn_exp2f(-2.8853900817779268f * x);
    return fmaf(2.0f, __builtin_amdgcn_rcpf(1.0f + e), -1.0f);
}
__device__ __forceinline__ __bf16 tobf(float f) { return (__bf16)f; }

// K-layout (K=32): k 0..12 = input part (x/xh/h0), k 13..15 = 0,
//                  k 16..28 = hidden part (h),     k 29..31 = 0.
// N-layout: gate g occupies its own 16-wide N-tile, cols 0..12 valid.
// Staging row stride: 24 bf16 = 48 B (16-B aligned for ds_read_b128).

__global__ __launch_bounds__(256, 2)
void lstm_fused(const float* __restrict__ x,
                const float* __restrict__ w_hidden,
                const float* __restrict__ b_hidden,
                const float* __restrict__ k0,
                const float* __restrict__ b0,
                const float* __restrict__ k1,
                const float* __restrict__ b1,
                const float* __restrict__ w_out,
                const float* __restrict__ b_out,
                float* __restrict__ out)
{
    // per-wave private staging: [wave][state][16 rows * 24 bf16]
    // states: 0 xh_hi, 1 xh_lo, 2 h0_hi, 3 h0_lo, 4 h1_hi, 5 h1_lo
    __shared__ __attribute__((aligned(16))) __bf16 stage[4][6][16 * 24];

    const int lane = threadIdx.x & 63;
    const int wv   = threadIdx.x >> 6;
    const int col  = lane & 15;   // n for B/C-frags, m for A-frags
    const int q    = lane >> 4;   // quad
    const int qh   = q & 1;
    const int s0   = (blockIdx.x * 4 + wv) * 16;

    // ---- weight B-fragments in VGPRs, hi/lo bf16 split ----
    bf16x8 K0h[4], K0l[4], K1h[4], K1l[4], Ph, Pl, Oh, Ol;
    #pragma unroll
    for (int g = 0; g < 4; ++g) {
        bf16x8 h0v{}, l0v{}, h1v{}, l1v{};
        #pragma unroll
        for (int j = 0; j < 8; ++j) {
            int k = 8 * q + j;
            float w0 = 0.f, w1 = 0.f;
            if (col < 13) {
                int rr = -1;
                if (k < 13) rr = k;                       // input-part rows
                else if (k >= 16 && k < 29) rr = 13 + (k - 16);  // hidden-part rows
                if (rr >= 0) {
                    w0 = k0[rr * 52 + 13 * g + col];
                    w1 = k1[rr * 52 + 13 * g + col];
                }
            }
            __bf16 hb0 = tobf(w0); h0v[j] = hb0; l0v[j] = tobf(w0 - (float)hb0);
            __bf16 hb1 = tobf(w1); h1v[j] = hb1; l1v[j] = tobf(w1 - (float)hb1);
        }
        K0h[g] = h0v; K0l[g] = l0v; K1h[g] = h1v; K1l[g] = l1v;
    }
    {
        bf16x8 hv{}, lv{}, ho{}, lo_{};
        #pragma unroll
        for (int j = 0; j < 8; ++j) {
            int k = 8 * q + j;
            float wp = (k < 13 && col < 13) ? w_hidden[k * 13 + col] : 0.f;
            float wo = (k < 13 && col < 4)  ? w_out[k * 4 + col]     : 0.f;
            __bf16 hb = tobf(wp); hv[j] = hb; lv[j]  = tobf(wp - (float)hb);
            __bf16 ob = tobf(wo); ho[j] = ob; lo_[j] = tobf(wo - (float)ob);
        }
        Ph = hv; Pl = lv; Oh = ho; Ol = lo_;
    }

    // ---- per-lane (per-column) biases ----
    const float bp  = (col < 13) ? b_hidden[col]   : 0.f;
    const float bi0 = (col < 13) ? b0[col]         : 0.f;
    const float bj0 = (col < 13) ? b0[13 + col]    : 0.f;
    const float bf0 = (col < 13) ? b0[26 + col]    : 0.f;
    const float bo0 = (col < 13) ? b0[39 + col]    : 0.f;
    const float bi1 = (col < 13) ? b1[col]         : 0.f;
    const float bj1 = (col < 13) ? b1[13 + col]    : 0.f;
    const float bf1 = (col < 13) ? b1[26 + col]    : 0.f;
    const float bo1 = (col < 13) ? b1[39 + col]    : 0.f;
    const float bob = (col < 4)  ? b_out[col]      : 0.f;

    // ---- zero staging (pad columns/rows must be exact bf16 zeros) ----
    {
        __bf16* sb = &stage[wv][0][0];
        for (int i = lane; i < 6 * 16 * 24; i += 64) sb[i] = (__bf16)0.f;
    }
    __bf16* stXH = &stage[wv][0][0];
    __bf16* stXL = &stage[wv][1][0];
    __bf16* st0H = &stage[wv][2][0];
    __bf16* st0L = &stage[wv][3][0];
    __bf16* st1H = &stage[wv][4][0];
    __bf16* st1L = &stage[wv][5][0];

    const float* xrow = x + (size_t)(s0 + col) * 1300;  // 100*13 floats per sample

    auto ldx = [&](float v[8], int tt) {
        #pragma unroll
        for (int j = 0; j < 8; ++j) v[j] = 0.f;
        if (q < 2) {
            const float* p = xrow + tt * 13 + 8 * q;
            #pragma unroll
            for (int j = 0; j < 8; ++j)
                if (8 * q + j < 13) v[j] = p[j];
        }
    };

    float xc[8], xn[8];
    ldx(xc, 0);

    f32x4 c0 = {0.f, 0.f, 0.f, 0.f};
    f32x4 c1 = {0.f, 0.f, 0.f, 0.f};

    for (int t = 0; t < 100; ++t) {
        // software-prefetch next step's x (hidden behind this step's compute)
        ldx(xn, (t < 99) ? t + 1 : 99);

        // ---- input projection: xh = relu(x_t @ w_hidden + b_hidden) ----
        bf16x8 axh, axl;
        #pragma unroll
        for (int j = 0; j < 8; ++j) {
            float v = (q < 2) ? xc[j] : 0.f;
            __bf16 hb = tobf(v);
            axh[j] = hb; axl[j] = tobf(v - (float)hb);
        }
        f32x4 zp = {bp, bp, bp, bp};
        zp = MFMA16(axh, Ph, zp);
        zp = MFMA16(axl, Ph, zp);
        zp = MFMA16(axh, Pl, zp);
        #pragma unroll
        for (int r = 0; r < 4; ++r) {
            float v = fmaxf(zp[r], 0.f);
            __bf16 hb = tobf(v);
            int row = 4 * q + r;
            stXH[row * 24 + col] = hb;
            stXL[row * 24 + col] = tobf(v - (float)hb);
        }

        // ---- lstm0: A = [xh ; h0_prev] ----
        {
            const __bf16* aH = (q < 2) ? stXH : st0H;
            const __bf16* aL = (q < 2) ? stXL : st0L;
            bf16x8 ah = *(const bf16x8*)(aH + col * 24 + 8 * qh);
            bf16x8 al = *(const bf16x8*)(aL + col * 24 + 8 * qh);
            f32x4 zi = {bi0, bi0, bi0, bi0};
            f32x4 zj = {bj0, bj0, bj0, bj0};
            f32x4 zf = {bf0, bf0, bf0, bf0};
            f32x4 zo = {bo0, bo0, bo0, bo0};
            zi = MFMA16(ah, K0h[0], zi); zi = MFMA16(al, K0h[0], zi); zi = MFMA16(ah, K0l[0], zi);
            zj = MFMA16(ah, K0h[1], zj); zj = MFMA16(al, K0h[1], zj); zj = MFMA16(ah, K0l[1], zj);
            zf = MFMA16(ah, K0h[2], zf); zf = MFMA16(al, K0h[2], zf); zf = MFMA16(ah, K0l[2], zf);
            zo = MFMA16(ah, K0h[3], zo); zo = MFMA16(al, K0h[3], zo); zo = MFMA16(ah, K0l[3], zo);
            #pragma unroll
            for (int r = 0; r < 4; ++r) {
                float si = fsig(zi[r]);
                float tj = ftanh(zj[r]);
                float sf = fsig(zf[r] + 1.0f);   // FORGET_BIAS
                float so = fsig(zo[r]);
                float cn = fmaf(c0[r], sf, si * tj);
                c0[r] = cn;
                float hv = ftanh(cn) * so;
                __bf16 hb = tobf(hv);
                int row = 4 * q + r;
                st0H[row * 24 + col] = hb;
                st0L[row * 24 + col] = tobf(hv - (float)hb);
            }
        }

        // ---- lstm1: A = [h0_new ; h1_prev] ----
        {
            const __bf16* aH = (q < 2) ? st0H : st1H;
            const __bf16* aL = (q < 2) ? st0L : st1L;
            bf16x8 ah = *(const bf16x8*)(aH + col * 24 + 8 * qh);
            bf16x8 al = *(const bf16x8*)(aL + col * 24 + 8 * qh);
            f32x4 zi = {bi1, bi1, bi1, bi1};
            f32x4 zj = {bj1, bj1, bj1, bj1};
            f32x4 zf = {bf1, bf1, bf1, bf1};
            f32x4 zo = {bo1, bo1, bo1, bo1};
            zi = MFMA16(ah, K1h[0], zi); zi = MFMA16(al, K1h[0], zi); zi = MFMA16(ah, K1l[0], zi);
            zj = MFMA16(ah, K1h[1], zj); zj = MFMA16(al, K1h[1], zj); zj = MFMA16(ah, K1l[1], zj);
            zf = MFMA16(ah, K1h[2], zf); zf = MFMA16(al, K1h[2], zf); zf = MFMA16(ah, K1l[2], zf);
            zo = MFMA16(ah, K1h[3], zo); zo = MFMA16(al, K1h[3], zo); zo = MFMA16(ah, K1l[3], zo);
            #pragma unroll
            for (int r = 0; r < 4; ++r) {
                float si = fsig(zi[r]);
                float tj = ftanh(zj[r]);
                float sf = fsig(zf[r] + 1.0f);
                float so = fsig(zo[r]);
                float cn = fmaf(c1[r], sf, si * tj);
                c1[r] = cn;
                float hv = ftanh(cn) * so;
                __bf16 hb = tobf(hv);
                int row = 4 * q + r;
                st1H[row * 24 + col] = hb;
                st1L[row * 24 + col] = tobf(hv - (float)hb);
            }
        }

        #pragma unroll
        for (int j = 0; j < 8; ++j) xc[j] = xn[j];
    }

    // ---- output projection: out = h1 @ w_out + b_out ----
    // q>=2 lanes read h1 again, but Oh/Ol rows k>=13 are zero -> contribute 0.
    bf16x8 afh = *(const bf16x8*)(st1H + col * 24 + 8 * qh);
    bf16x8 afl = *(const bf16x8*)(st1L + col * 24 + 8 * qh);
    f32x4 zfin = {bob, bob, bob, bob};
    zfin = MFMA16(afh, Oh, zfin);
    zfin = MFMA16(afl, Oh, zfin);
    zfin = MFMA16(afh, Ol, zfin);
    if (col < 4) {
        #pragma unroll
        for (int r = 0; r < 4; ++r)
            out[(size_t)(s0 + 4 * q + r) * 4 + col] = zfin[r];
    }
}

extern "C" void kernel_launch(void* const* d_in, const int* in_sizes, int n_in,
                              void* d_out, int out_size, void* d_ws, size_t ws_size,
                              hipStream_t stream) {
    (void)in_sizes; (void)n_in; (void)d_ws; (void)ws_size; (void)out_size;
    lstm_fused<<<dim3(512), dim3(256), 0, stream>>>(
        (const float*)d_in[0], (const float*)d_in[1], (const float*)d_in[2],
        (const float*)d_in[3], (const float*)d_in[4], (const float*)d_in[5],
        (const float*)d_in[6], (const float*)d_in[7], (const float*)d_in[8],
        (float*)d_out);
}

// Round 2
// 380.586 us; speedup vs baseline: 1.1583x; 1.1583x over previous
//
#include <hip/hip_runtime.h>
#include <cstdint>

typedef __bf16          bf16x8 __attribute__((ext_vector_type(8)));
typedef float           f32x4  __attribute__((ext_vector_type(4)));
typedef unsigned short  u16x8  __attribute__((ext_vector_type(8)));

#define MFMA16(a, b, c) __builtin_amdgcn_mfma_f32_16x16x32_bf16((a), (b), (c), 0, 0, 0)

__device__ __forceinline__ float fsig(float x) {
    float e = __builtin_amdgcn_exp2f(-1.4426950408889634f * x);
    return __builtin_amdgcn_rcpf(1.0f + e);
}
__device__ __forceinline__ float ftanh(float x) {
    float e = __builtin_amdgcn_exp2f(-2.8853900817779268f * x);
    return fmaf(2.0f, __builtin_amdgcn_rcpf(1.0f + e), -1.0f);
}
// truncation hi/lo split: hi = top16(v), lo = trunc16(v - hi). Pair represents v
// to ~2^-16 relative; MFMA(hh + hl + lh) recovers fp32-ish product. Cheap: 4 VALU.
__device__ __forceinline__ void split2(float v, unsigned short& hi, unsigned short& lo) {
    unsigned u = __builtin_bit_cast(unsigned, v);
    hi = (unsigned short)(u >> 16);
    float rem = v - __builtin_bit_cast(float, u & 0xffff0000u);
    lo = (unsigned short)(__builtin_bit_cast(unsigned, rem) >> 16);
}

// Layer-pipelined 2-layer LSTM.
// Block = 4 waves = 2 sample-groups x 2 roles. Role 0: lstm0 step i.
// Role 1: lstm1 step i-1 + input projection step i+1. h0/xh cross waves via
// double-buffered LDS in shared A-fragment staging layout (row m = sample,
// 24-ushort row stride, hi/lo planes). One __syncthreads per step.
// K-layout (K=32): k0..12 input part, k13..15 zero, k16..28 hidden, k29..31 zero.
// Each gate g has its own 16-wide N-tile (cols 0..12 valid).

__global__ __launch_bounds__(256, 4)
void lstm_fused(const float* __restrict__ x,
                const float* __restrict__ w_hidden,
                const float* __restrict__ b_hidden,
                const float* __restrict__ k0,
                const float* __restrict__ b0,
                const float* __restrict__ k1,
                const float* __restrict__ b1,
                const float* __restrict__ w_out,
                const float* __restrict__ b_out,
                float* __restrict__ out)
{
    // [group][buf][plane(hi/lo)][16 rows * 24]
    __shared__ __attribute__((aligned(16))) unsigned short xh_s[2][2][2][384];
    __shared__ __attribute__((aligned(16))) unsigned short h0_s[2][2][2][384];
    __shared__ __attribute__((aligned(16))) unsigned short h1_s[2][2][384];

    const int lane = threadIdx.x & 63;
    const int wv   = threadIdx.x >> 6;
    const int grp  = wv >> 1;
    const int role = wv & 1;
    const int col  = lane & 15;
    const int q    = lane >> 4;
    const int qh   = q & 1;
    const int s0   = (blockIdx.x * 2 + grp) * 16;

    // ---- zero-init cross-step state images ----
    for (int i = threadIdx.x; i < 2 * 2 * 2 * 384; i += 256) ((unsigned short*)h0_s)[i] = 0;
    for (int i = threadIdx.x; i < 2 * 2 * 384;     i += 256) ((unsigned short*)h1_s)[i] = 0;

    // ---- role-selected LSTM weights as B-fragments (hi/lo) ----
    const float* kp = role ? k1 : k0;
    const float* bb = role ? b1 : b0;
    bf16x8 Kh[4], Kl[4];
    #pragma unroll
    for (int g = 0; g < 4; ++g) {
        bf16x8 hv{}, lv{};
        #pragma unroll
        for (int j = 0; j < 8; ++j) {
            int k = 8 * q + j;
            float w = 0.f;
            if (col < 13) {
                int rr = -1;
                if (k < 13) rr = k;
                else if (k >= 16 && k < 29) rr = 13 + (k - 16);
                if (rr >= 0) w = kp[rr * 52 + 13 * g + col];
            }
            unsigned short h_, l_;
            split2(w, h_, l_);
            hv[j] = __builtin_bit_cast(__bf16, h_);
            lv[j] = __builtin_bit_cast(__bf16, l_);
        }
        Kh[g] = hv; Kl[g] = lv;
    }
    const float bi  = (col < 13) ? bb[col]      : 0.f;
    const float bj  = (col < 13) ? bb[13 + col] : 0.f;
    const float bf_ = (col < 13) ? bb[26 + col] : 0.f;
    const float bo_ = (col < 13) ? bb[39 + col] : 0.f;

    // ---- proj/output weights (role 1 only; uniform branch) ----
    bf16x8 Ph{}, Pl{}, Oh{}, Ol{};
    float bp = 0.f, bob = 0.f;
    if (role) {
        #pragma unroll
        for (int j = 0; j < 8; ++j) {
            int k = 8 * q + j;
            float wp = (k < 13 && col < 13) ? w_hidden[k * 13 + col] : 0.f;
            float wo = (k < 13 && col < 4)  ? w_out[k * 4 + col]     : 0.f;
            unsigned short h_, l_;
            split2(wp, h_, l_); Ph[j] = __builtin_bit_cast(__bf16, h_); Pl[j] = __builtin_bit_cast(__bf16, l_);
            split2(wo, h_, l_); Oh[j] = __builtin_bit_cast(__bf16, h_); Ol[j] = __builtin_bit_cast(__bf16, l_);
        }
        bp  = (col < 13) ? b_hidden[col] : 0.f;
        bob = (col < 4)  ? b_out[col]    : 0.f;
    }

    const float* xrow = x + (size_t)(s0 + col) * 1300;  // 100*13 floats/sample
    const int ro = 4 * q * 24 + col;                    // staging row-base offset

    auto do_proj = [&](int t, unsigned short* oH, unsigned short* oL) {
        const float* p = xrow + t * 13;
        float xv[8];
        #pragma unroll
        for (int j = 0; j < 8; ++j) xv[j] = 0.f;
        if (q == 0) {
            #pragma unroll
            for (int j = 0; j < 8; ++j) xv[j] = p[j];
        } else if (q == 1) {
            #pragma unroll
            for (int j = 0; j < 5; ++j) xv[j] = p[8 + j];
        }
        bf16x8 axh, axl;
        #pragma unroll
        for (int j = 0; j < 8; ++j) {
            unsigned short h_, l_;
            split2(xv[j], h_, l_);
            axh[j] = __builtin_bit_cast(__bf16, h_);
            axl[j] = __builtin_bit_cast(__bf16, l_);
        }
        f32x4 zp = {bp, bp, bp, bp};
        zp = MFMA16(axh, Ph, zp);
        zp = MFMA16(axl, Ph, zp);
        zp = MFMA16(axh, Pl, zp);
        #pragma unroll
        for (int r = 0; r < 4; ++r) {
            float v = fmaxf(zp[r], 0.f);
            unsigned short hh, hl;
            split2(v, hh, hl);
            oH[ro + r * 24] = hh;
            oL[ro + r * 24] = hl;
        }
    };

    auto do_cell = [&](const unsigned short* inH, const unsigned short* inL,
                       const unsigned short* hidH, const unsigned short* hidL,
                       f32x4& cst, unsigned short* oH, unsigned short* oL) {
        const unsigned short* pH = (q < 2) ? inH : hidH;
        const unsigned short* pL = (q < 2) ? inL : hidL;
        bf16x8 ah = __builtin_bit_cast(bf16x8, *(const u16x8*)(pH + col * 24 + 8 * qh));
        bf16x8 al = __builtin_bit_cast(bf16x8, *(const u16x8*)(pL + col * 24 + 8 * qh));
        f32x4 zi = {bi, bi, bi, bi};
        f32x4 zj = {bj, bj, bj, bj};
        f32x4 zf = {bf_, bf_, bf_, bf_};
        f32x4 zo = {bo_, bo_, bo_, bo_};
        zi = MFMA16(ah, Kh[0], zi); zi = MFMA16(al, Kh[0], zi); zi = MFMA16(ah, Kl[0], zi);
        zj = MFMA16(ah, Kh[1], zj); zj = MFMA16(al, Kh[1], zj); zj = MFMA16(ah, Kl[1], zj);
        zf = MFMA16(ah, Kh[2], zf); zf = MFMA16(al, Kh[2], zf); zf = MFMA16(ah, Kl[2], zf);
        zo = MFMA16(ah, Kh[3], zo); zo = MFMA16(al, Kh[3], zo); zo = MFMA16(ah, Kl[3], zo);
        #pragma unroll
        for (int r = 0; r < 4; ++r) {
            float si = fsig(zi[r]);
            float tj = ftanh(zj[r]);
            float sf = fsig(zf[r] + 1.0f);   // FORGET_BIAS
            float so = fsig(zo[r]);
            float cn = fmaf(cst[r], sf, si * tj);
            cst[r] = cn;
            float hv = ftanh(cn) * so;
            unsigned short hh, hl;
            split2(hv, hh, hl);
            oH[ro + r * 24] = hh;
            oL[ro + r * 24] = hl;
        }
    };

    f32x4 cst = {0.f, 0.f, 0.f, 0.f};

    // ---- prologue: proj(0) into xh buf 0 ----
    if (role) do_proj(0, &xh_s[grp][0][0][0], &xh_s[grp][0][1][0]);
    __syncthreads();

    for (int i = 0; i <= 100; ++i) {
        if (role == 0) {
            if (i < 100) {
                int rb = i & 1, pb = (i + 1) & 1;   // pb == (i-1)&1
                do_cell(&xh_s[grp][rb][0][0], &xh_s[grp][rb][1][0],
                        &h0_s[grp][pb][0][0], &h0_s[grp][pb][1][0],
                        cst,
                        &h0_s[grp][rb][0][0], &h0_s[grp][rb][1][0]);
            }
        } else {
            if (i >= 1) {
                int rb = (i - 1) & 1;               // h0 buffer for step i-1
                do_cell(&h0_s[grp][rb][0][0], &h0_s[grp][rb][1][0],
                        &h1_s[grp][0][0], &h1_s[grp][1][0],
                        cst,
                        &h1_s[grp][0][0], &h1_s[grp][1][0]);
            }
            if (i < 99) {
                int tb = (i + 1) & 1;
                do_proj(i + 1, &xh_s[grp][tb][0][0], &xh_s[grp][tb][1][0]);
            }
        }
        __syncthreads();
    }

    // ---- output projection (role 1 holds final h1) ----
    if (role) {
        const unsigned short* pH = &h1_s[grp][0][0];
        const unsigned short* pL = &h1_s[grp][1][0];
        // q>=2 lanes re-read h1, but Oh/Ol rows k>=13 are zero -> contribute 0.
        bf16x8 afh = __builtin_bit_cast(bf16x8, *(const u16x8*)(pH + col * 24 + 8 * qh));
        bf16x8 afl = __builtin_bit_cast(bf16x8, *(const u16x8*)(pL + col * 24 + 8 * qh));
        f32x4 zfin = {bob, bob, bob, bob};
        zfin = MFMA16(afh, Oh, zfin);
        zfin = MFMA16(afl, Oh, zfin);
        zfin = MFMA16(afh, Ol, zfin);
        if (col < 4) {
            #pragma unroll
            for (int r = 0; r < 4; ++r)
                out[(size_t)(s0 + 4 * q + r) * 4 + col] = zfin[r];
        }
    }
}

extern "C" void kernel_launch(void* const* d_in, const int* in_sizes, int n_in,
                              void* d_out, int out_size, void* d_ws, size_t ws_size,
                              hipStream_t stream) {
    (void)in_sizes; (void)n_in; (void)d_ws; (void)ws_size; (void)out_size;
    lstm_fused<<<dim3(1024), dim3(256), 0, stream>>>(
        (const float*)d_in[0], (const float*)d_in[1], (const float*)d_in[2],
        (const float*)d_in[3], (const float*)d_in[4], (const float*)d_in[5],
        (const float*)d_in[6], (const float*)d_in[7], (const float*)d_in[8],
        (float*)d_out);
}